// Round 1
// 1765.282 us; speedup vs baseline: 1.3804x; 1.3804x over previous
//
#include <hip/hip_runtime.h>

#define T_STEPS 512
#define BATCH   128
#define SDIM    1024
#define ODIM    256
#define NWG     80            // 64 g1 (8 groups x 8 producers) + 16 g2 (8 groups x 2)
#define NG1     64
#define NTHR    512           // 8 waves

typedef __attribute__((ext_vector_type(8))) short bf16x8;
typedef __attribute__((ext_vector_type(4))) float f32x4;
typedef __attribute__((ext_vector_type(4))) unsigned int u32x4;

// ws layout (bytes)
#define WR_OFF   0                         // ushort[1024*1024]  2 MB (w_r bf16)
#define WO_OFF   (2u*1024*1024)            // ushort[256*1024] 512 KB (w_o bf16)
#define H_OFF    (WO_OFF + 512u*1024)      // float [128*1024] 512 KB (h state)
#define TH_OFF   (H_OFF + 512u*1024)       // 4 x 256 KB th buffers (4-deep)
#define TH_WORDS (128u*1024)               // ushorts per buffer
#define FLAG_OFF (TH_OFF + 4u*2u*TH_WORDS) // unsigned flags[NWG], 64 B apart
#define FLAG_STRIDE 16

#define LDS_ROW  1032                      // 1024 shorts + 16 B pad per row

// th buffer layout (per buffer, ushort units):
//   group g (16 batch rows) block: g*16384
//   producer p block:             + p*2048     (p = j >> 7)
//   batch row b (0..15):          + b*128
//   local j' (0..127):            + j'
// -> each producer thread's 4 outputs (consecutive j) are ONE aligned 8 B store,
//    and each [b] row is j-contiguous per p-block for 16 B staging loads.

__device__ __forceinline__ unsigned short f2bf(float f) {
    union { float f; unsigned u; } v; v.f = f;
    unsigned r = v.u + 0x7fffu + ((v.u >> 16) & 1u);   // round-to-nearest-even
    return (unsigned short)(r >> 16);
}

// sc1 (device-coherent) 16 B load: bypasses per-XCD L2, serviced at L3.
#define LOAD16_SC1(d, p) \
    asm volatile("global_load_dwordx4 %0, %1, off sc0 sc1" : "=v"(d) : "v"(p))
#define WAIT_HOLD4(a,b,c,d)                                            \
    asm volatile("s_waitcnt vmcnt(0)"                                  \
                 : "+v"(a), "+v"(b), "+v"(c), "+v"(d) :: "memory")

__device__ __forceinline__ void st_sc1_u16(unsigned short* p, unsigned short v) {
    __hip_atomic_store(p, v, __ATOMIC_RELAXED, __HIP_MEMORY_SCOPE_AGENT);
}
__device__ __forceinline__ void st_sc1_f32(float* p, float v) {
    __hip_atomic_store(p, v, __ATOMIC_RELAXED, __HIP_MEMORY_SCOPE_AGENT);
}
__device__ __forceinline__ void st_sc1_u64(unsigned long long* p, unsigned long long v) {
    __hip_atomic_store(p, v, __ATOMIC_RELAXED, __HIP_MEMORY_SCOPE_AGENT);
}
__device__ __forceinline__ unsigned ld_flag(const unsigned* p) {
    return __hip_atomic_load(p, __ATOMIC_RELAXED, __HIP_MEMORY_SCOPE_AGENT);
}
__device__ __forceinline__ void post_flag(unsigned* p, unsigned v) {
    __hip_atomic_store(p, v, __ATOMIC_RELAXED, __HIP_MEMORY_SCOPE_AGENT);
}

// Stage one group's [16 x 1024] th tile (producer-major global layout) into LDS
// rows [b][j]. 512 threads x 4 x 16 B loads. No transpose needed: within a
// p-block rows are j-contiguous.
__device__ __forceinline__ void stage_tile(const unsigned short* __restrict__ gsrc,
                                           unsigned short* __restrict__ lds, int tid) {
    const int r_st = tid >> 5;      // batch row 0..15
    const int c0   = tid & 31;      // chunk col; chunk c = c0 + 32k, j = c*8
    const unsigned short* src = gsrc + (c0 >> 4) * 2048 + r_st * 128 + (c0 & 15) * 8;
    u32x4 d0, d1, d2, d3;
    LOAD16_SC1(d0, src + 0 * 4096);   // k: p advances by 2 -> +4096 ushorts
    LOAD16_SC1(d1, src + 1 * 4096);
    LOAD16_SC1(d2, src + 2 * 4096);
    LOAD16_SC1(d3, src + 3 * 4096);
    WAIT_HOLD4(d0, d1, d2, d3);
    unsigned short* dst = lds + r_st * LDS_ROW + c0 * 8;
    *(u32x4*)(dst + 0 * 256) = d0;
    *(u32x4*)(dst + 1 * 256) = d1;
    *(u32x4*)(dst + 2 * 256) = d2;
    *(u32x4*)(dst + 3 * 256) = d3;
}

__global__ __launch_bounds__(NTHR, 2) void trnn_persistent(
    const float* __restrict__ x, const float* __restrict__ h_init,
    const float* __restrict__ w_r, const float* __restrict__ b_r,
    const float* __restrict__ w_o, const float* __restrict__ b_o,
    float* __restrict__ out, char* __restrict__ ws)
{
    unsigned short* wr_bf = (unsigned short*)(ws + WR_OFF);
    unsigned short* wo_bf = (unsigned short*)(ws + WO_OFF);
    float*          hbuf  = (float*)(ws + H_OFF);
    unsigned short* thb   = (unsigned short*)(ws + TH_OFF);
    unsigned*       flags = (unsigned*)(ws + FLAG_OFF);

    __shared__ unsigned short lds_th[16 * LDS_ROW];   // 33 KB

    const int wg   = blockIdx.x;
    const int tid  = threadIdx.x;
    const int gtid = wg * NTHR + tid;
    const int gstr = NWG * NTHR;

    // ---- init: bf16 weights, h state, th_0 (new layout) into buffer 0 ----
    for (int i = gtid; i < SDIM * SDIM; i += gstr) st_sc1_u16(&wr_bf[i], f2bf(w_r[i]));
    for (int i = gtid; i < ODIM * SDIM; i += gstr) st_sc1_u16(&wo_bf[i], f2bf(w_o[i]));
    for (int i = gtid; i < BATCH * SDIM; i += gstr) {
        const int b = i >> 10, j = i & 1023;
        float v = h_init[i];
        st_sc1_f32(&hbuf[i], v);
        const int dst = (b >> 4) * 16384 + (j >> 7) * 2048 + (b & 15) * 128 + (j & 127);
        st_sc1_u16(&thb[dst], f2bf(tanhf(v)));
    }

    // ---- global barrier after init ----
    {
        asm volatile("s_waitcnt vmcnt(0)" ::: "memory");
        __syncthreads();
        if (tid == 0) post_flag(&flags[wg * FLAG_STRIDE], 1u);
        if (tid < NWG) {
            while (ld_flag(&flags[tid * FLAG_STRIDE]) < 1u) {}
        }
        __syncthreads();
    }

    const int lane = tid & 63;
    const int wv   = tid >> 6;          // wave 0..7
    const int row  = lane & 15;         // = batch-within-group (D col after swap)
    const int quad = lane >> 4;

    const bool is_g1 = (wg < NG1);
    const int g  = is_g1 ? (wg >> 3) : ((wg - NG1) >> 1);
    const int p  = is_g1 ? (wg & 7)  : ((wg - NG1) & 1);
    const int jb = p * 128 + wv * 16;   // this wave's j (or o) base

    // ---- weight-stationary A-fragments: w[jb+row][k], 128 regs/lane ----
    const unsigned short* bsrc =
        (is_g1 ? wr_bf + (jb + row) * SDIM
               : wo_bf + (jb + row) * SDIM) + quad * 8;
    bf16x8 bw[32];
    #pragma unroll
    for (int kk = 0; kk < 32; ++kk) bw[kk] = *(const bf16x8*)(bsrc + kk * 32);

    if (is_g1) {
        const int j0 = jb + quad * 4;           // 4 consecutive output j
        const int gb = g * 16 + row;            // global batch row
        float* hrow = hbuf + gb * SDIM;
        const f32x4 brv = *(const f32x4*)&b_r[j0];
        // this thread's 8 B th-slot offset (ushorts, within a buffer)
        const int slot = g * 16384 + p * 2048 + row * 128 + (wv * 16 + quad * 4);

        for (int t = 0; t < T_STEPS; ++t) {
            const f32x4 hv = *(const f32x4*)&hrow[j0];   // own data: pre-poll OK
            // poll: lanes 0..7 peers' data (>= t+1); lanes 8..9 lagged g2
            // anti-dep (>= t-1, buffer written this iter held th_{t-3})
            if (tid < 10) {
                const int fid = (tid < 8) ? (g * 8 + tid) : (NG1 + g * 2 + (tid - 8));
                const unsigned tgt = (tid < 8) ? (unsigned)(t + 1)
                                               : (t >= 3 ? (unsigned)(t - 1) : 0u);
                while (ld_flag(&flags[fid * FLAG_STRIDE]) < tgt) {}
            }
            __syncthreads();

            const unsigned short* cur = thb + (t & 3) * TH_WORDS + g * 16384;
            stage_tile(cur, lds_th, tid);
            __syncthreads();

            // D[j][b] = sum_k w[j][k] th[b][k]  (operand-swapped MFMA)
            f32x4 acc = {0.f, 0.f, 0.f, 0.f};
            const unsigned short* arow = &lds_th[row * LDS_ROW + quad * 8];
            #pragma unroll
            for (int kk = 0; kk < 32; ++kk) {
                bf16x8 tf = *(const bf16x8*)(arow + kk * 32);
                acc = __builtin_amdgcn_mfma_f32_16x16x32_bf16(bw[kk], tf, acc, 0, 0, 0);
            }

            // h' = 0.75 h + 0.25 (th w_r^T + b_r); th' packed as one 8 B store
            f32x4 hn;
            #pragma unroll
            for (int r = 0; r < 4; ++r)
                hn[r] = 0.75f * hv[r] + 0.25f * (acc[r] + brv[r]);
            *(f32x4*)&hrow[j0] = hn;             // private: normal store
            unsigned long long pk =
                  (unsigned long long)f2bf(tanhf(hn[0]))
                | ((unsigned long long)f2bf(tanhf(hn[1])) << 16)
                | ((unsigned long long)f2bf(tanhf(hn[2])) << 32)
                | ((unsigned long long)f2bf(tanhf(hn[3])) << 48);
            unsigned short* nxt = thb + ((t + 1) & 3) * TH_WORDS;
            st_sc1_u64((unsigned long long*)(nxt + slot), pk);

            asm volatile("s_waitcnt vmcnt(0)" ::: "memory");
            __syncthreads();
            if (tid == 0) post_flag(&flags[wg * FLAG_STRIDE], (unsigned)(t + 2));
        }
    } else {
        const int o0 = jb + quad * 4;           // 4 consecutive output o
        const int gb = g * 16 + row;
        const f32x4 bov = *(const f32x4*)&b_o[o0];
        if (tid == 0) post_flag(&flags[wg * FLAG_STRIDE], 2u);  // "iter 0 done"

        for (int t = 1; t <= T_STEPS; ++t) {
            const int xbase = (t - 1) * BATCH * ODIM + gb * ODIM + o0;
            const f32x4 xv = *(const f32x4*)&x[xbase];  // flag-independent: pre-poll
            if (tid < 8) {
                while (ld_flag(&flags[(g * 8 + tid) * FLAG_STRIDE]) < (unsigned)(t + 1)) {}
            }
            __syncthreads();

            const unsigned short* cur = thb + (t & 3) * TH_WORDS + g * 16384;
            stage_tile(cur, lds_th, tid);
            __syncthreads();
            // reads of th_t are complete (loads drained per-thread before the
            // barrier) -> post read-done flag BEFORE compute/out-stores
            if (tid == 0) post_flag(&flags[wg * FLAG_STRIDE], (unsigned)(t + 2));

            f32x4 acc = {0.f, 0.f, 0.f, 0.f};
            const unsigned short* arow = &lds_th[row * LDS_ROW + quad * 8];
            #pragma unroll
            for (int kk = 0; kk < 32; ++kk) {
                bf16x8 tf = *(const bf16x8*)(arow + kk * 32);
                acc = __builtin_amdgcn_mfma_f32_16x16x32_bf16(bw[kk], tf, acc, 0, 0, 0);
            }
            f32x4 ov;
            #pragma unroll
            for (int r = 0; r < 4; ++r) ov[r] = acc[r] + bov[r] - xv[r];
            *(f32x4*)&out[xbase] = ov;           // coalesced 16 B store
        }
    }
}

extern "C" void kernel_launch(void* const* d_in, const int* in_sizes, int n_in,
                              void* d_out, int out_size, void* d_ws, size_t ws_size,
                              hipStream_t stream) {
    const float* x      = (const float*)d_in[0];
    const float* h_init = (const float*)d_in[1];
    const float* w_r    = (const float*)d_in[2];
    const float* b_r    = (const float*)d_in[3];
    const float* w_o    = (const float*)d_in[4];
    const float* b_o    = (const float*)d_in[5];
    float* out = (float*)d_out;
    char*  ws  = (char*)d_ws;

    // zero the barrier flags (ws is poisoned 0xAA before every launch)
    (void)hipMemsetAsync(ws + FLAG_OFF, 0, NWG * 64, stream);

    trnn_persistent<<<dim3(NWG), dim3(NTHR), 0, stream>>>(
        x, h_init, w_r, b_r, w_o, b_o, out, ws);
}